// Round 9
// baseline (93.113 us; speedup 1.0000x reference)
//
#include <hip/hip_runtime.h>
#include <hip/hip_bf16.h>

#define N_NODES 120000
#define F       64

typedef __attribute__((ext_vector_type(8))) short bf16x8;   // 4 VGPRs
typedef __attribute__((ext_vector_type(4))) float f32x4;    // MFMA C/D
typedef __attribute__((ext_vector_type(4))) int   int4v;
typedef __attribute__((ext_vector_type(2))) float float2v;

static __device__ __forceinline__ unsigned short f2bf(float x) {
    return __hip_bfloat16_raw(__float2bfloat16(x)).x;   // RNE
}
static __device__ __forceinline__ float u2f(unsigned int x) {
    return __uint_as_float(x);
}

// Pack theta_w/phi_w into per-lane MFMA B-operand fragments (bf16).
__global__ void prep_weights(const float* __restrict__ theta_w,
                             const float* __restrict__ phi_w,
                             unsigned short* __restrict__ wfrag)  // [16][64][8]
{
    const int t    = threadIdx.x;          // 0..1023
    const int slot = t >> 6, lane = t & 63;
    const int mat  = slot >> 3, c = (slot >> 1) & 3, kb = slot & 1;
    const float* W = mat ? phi_w : theta_w;
    const int k0   = kb * 32 + ((lane >> 4) * 8);
    const int col  = c * 16 + (lane & 15);
    bf16x8 v;
    #pragma unroll
    for (int e = 0; e < 8; ++e)
        v[e] = (short)f2bf(W[(k0 + e) * F + col]);
    ((bf16x8*)wfrag)[slot * 64 + lane] = v;
}

// Kernel 1 (MFMA): Tc[c][r][16] = bf16(feat@theta), Bc[c][r][16] = bf16(T + feat@phi + biases)
// Column-chunked layouts; stores are non-temporal (consumed cross-XCD, don't pollute local L2).
__global__ __launch_bounds__(256) void edgeconv_mfma(
    const float* __restrict__ feat,
    const unsigned short* __restrict__ wfrag,
    const float* __restrict__ theta_b,
    const float* __restrict__ phi_b,
    unsigned short* __restrict__ Tc,   // [4][N][16] bf16
    unsigned short* __restrict__ Bc)   // [4][N][16] bf16
{
    const int lane = threadIdx.x & 63;
    const int wv   = threadIdx.x >> 6;
    const int tile = blockIdx.x * 4 + wv;
    const int r0   = tile * 16;

    const bf16x8* wf = (const bf16x8*)wfrag;
    bf16x8 wt[4][2], wp[4][2];
    #pragma unroll
    for (int c = 0; c < 4; ++c) {
        #pragma unroll
        for (int kb = 0; kb < 2; ++kb) {
            wt[c][kb] = wf[((0 * 4 + c) * 2 + kb) * 64 + lane];
            wp[c][kb] = wf[((1 * 4 + c) * 2 + kb) * 64 + lane];
        }
    }

    const int arow = r0 + (lane & 15);
    const int k0   = (lane >> 4) * 8;
    const float4* f0 = (const float4*)(feat + arow * F + k0);
    const float4* f1 = (const float4*)(feat + arow * F + 32 + k0);
    float4 a0 = f0[0], a1 = f0[1];
    float4 a2 = f1[0], a3 = f1[1];
    bf16x8 afr0, afr1;
    afr0[0]=(short)f2bf(a0.x); afr0[1]=(short)f2bf(a0.y); afr0[2]=(short)f2bf(a0.z); afr0[3]=(short)f2bf(a0.w);
    afr0[4]=(short)f2bf(a1.x); afr0[5]=(short)f2bf(a1.y); afr0[6]=(short)f2bf(a1.z); afr0[7]=(short)f2bf(a1.w);
    afr1[0]=(short)f2bf(a2.x); afr1[1]=(short)f2bf(a2.y); afr1[2]=(short)f2bf(a2.z); afr1[3]=(short)f2bf(a2.w);
    afr1[4]=(short)f2bf(a3.x); afr1[5]=(short)f2bf(a3.y); afr1[6]=(short)f2bf(a3.z); afr1[7]=(short)f2bf(a3.w);

    f32x4 accT[4], accP[4];
    #pragma unroll
    for (int c = 0; c < 4; ++c) { accT[c] = (f32x4)(0.f); accP[c] = (f32x4)(0.f); }

    #pragma unroll
    for (int c = 0; c < 4; ++c) {
        accT[c] = __builtin_amdgcn_mfma_f32_16x16x32_bf16(afr0, wt[c][0], accT[c], 0, 0, 0);
        accT[c] = __builtin_amdgcn_mfma_f32_16x16x32_bf16(afr1, wt[c][1], accT[c], 0, 0, 0);
        accP[c] = __builtin_amdgcn_mfma_f32_16x16x32_bf16(afr0, wp[c][0], accP[c], 0, 0, 0);
        accP[c] = __builtin_amdgcn_mfma_f32_16x16x32_bf16(afr1, wp[c][1], accP[c], 0, 0, 0);
    }

    const int colbase = lane & 15;
    const int rowbase = (lane >> 4) * 4;
    #pragma unroll
    for (int c = 0; c < 4; ++c) {
        const int col  = c * 16 + colbase;
        const float bo = theta_b[col] + phi_b[col];
        #pragma unroll
        for (int rg = 0; rg < 4; ++rg) {
            const int r = r0 + rowbase + rg;
            const float t = accT[c][rg];
            __builtin_nontemporal_store((unsigned short)f2bf(t),
                                        Tc + (c * N_NODES + r) * 16 + colbase);
            __builtin_nontemporal_store((unsigned short)f2bf(t + accP[c][rg] + bo),
                                        Bc + (c * N_NODES + r) * 16 + colbase);
        }
    }
}

// Kernel 2: out[v][c*16+cc] = Bc[c][v][cc] - min_k Tc[c][nbr[v][k]][cc]
// XCD-pinned chunks (bid&7 -> XCD; XCD pair {2c,2c+1} owns chunk c, 3.84 MB).
// ALL streaming traffic (nbr, B, out) is non-temporal so the chunk stays L2-resident.
__global__ __launch_bounds__(256) void edgeconv_minmax(
    const int* __restrict__ nbr,              // [N,16] int32
    const unsigned short* __restrict__ Tc,    // [4][N][16] bf16
    const unsigned short* __restrict__ Bc,    // [4][N][16] bf16
    float* __restrict__ out)                  // [N,64] f32
{
    const int bid   = blockIdx.x;
    const int xcd   = bid & 7;
    const int chunk = xcd >> 1;
    const int ng    = (bid >> 3) * 2 + (xcd & 1);     // node-group 0..3749

    const int tid  = threadIdx.x;
    const int lane = tid & 63;
    const int wv   = tid >> 6;
    const int sub  = lane >> 3;      // node within wave, 0..7
    const int j    = lane & 7;       // column pair within chunk: cols 2j, 2j+1
    const int v    = ng * 32 + wv * 8 + sub;

    // 16 neighbor indices, non-temporal (8 lanes/node same addr -> broadcast)
    const int4v* nb4 = (const int4v*)(nbr + v * 16);
    int4v i0 = __builtin_nontemporal_load(nb4 + 0);
    int4v i1 = __builtin_nontemporal_load(nb4 + 1);
    int4v i2 = __builtin_nontemporal_load(nb4 + 2);
    int4v i3 = __builtin_nontemporal_load(nb4 + 3);
    int idx[16] = { i0[0], i0[1], i0[2], i0[3],
                    i1[0], i1[1], i1[2], i1[3],
                    i2[0], i2[1], i2[2], i2[3],
                    i3[0], i3[1], i3[2], i3[3] };

    const char* tbase = (const char*)Tc + (size_t)chunk * N_NODES * 32 + (j << 2);

    // 16 independent 4B gathers per lane (default caching: these are the L2-resident hits).
    unsigned int u[16];
    #pragma unroll
    for (int k = 0; k < 16; ++k)
        u[k] = *(const unsigned int*)(tbase + (((unsigned int)idx[k]) << 5));

    float mlo = u2f(u[0] << 16);
    float mhi = u2f(u[0] & 0xffff0000u);   // raw-high-half IS a valid f32 (<=2^-8 rel garbage)
    #pragma unroll
    for (int k = 1; k < 16; ++k) {
        mlo = fminf(mlo, u2f(u[k] << 16));
        mhi = fminf(mhi, u2f(u[k] & 0xffff0000u));
    }

    const unsigned int bu = __builtin_nontemporal_load((const unsigned int*)(
        (const char*)Bc + (size_t)chunk * N_NODES * 32 + (((unsigned int)v) << 5) + (j << 2)));
    const float blo = u2f(bu << 16);
    const float bhi = u2f(bu & 0xffff0000u);

    float2v res = { blo - mlo, bhi - mhi };
    __builtin_nontemporal_store(res, (float2v*)(out + v * F + chunk * 16 + 2 * j));
}

extern "C" void kernel_launch(void* const* d_in, const int* in_sizes, int n_in,
                              void* d_out, int out_size, void* d_ws, size_t ws_size,
                              hipStream_t stream) {
    const float* feat    = (const float*)d_in[0];
    const int*   nbr     = (const int*)  d_in[1];
    const float* theta_w = (const float*)d_in[2];
    const float* theta_b = (const float*)d_in[3];
    const float* phi_w   = (const float*)d_in[4];
    const float* phi_b   = (const float*)d_in[5];
    float* out = (float*)d_out;

    unsigned short* wfrag = (unsigned short*)d_ws;                        // 16 KB
    unsigned short* Tc    = (unsigned short*)((char*)d_ws + 16384);      // 15.36 MB
    unsigned short* Bc    = (unsigned short*)((char*)d_ws + 16384 + 15360000);

    prep_weights<<<1, 1024, 0, stream>>>(theta_w, phi_w, wfrag);
    edgeconv_mfma<<<N_NODES / 64, 256, 0, stream>>>(feat, wfrag, theta_b, phi_b, Tc, Bc);
    // 4 chunks x 3750 node-groups of 32 nodes = 15000 blocks
    edgeconv_minmax<<<15000, 256, 0, stream>>>(nbr, Tc, Bc, out);
}

// Round 10
// 55.459 us; speedup vs baseline: 1.6790x; 1.6790x over previous
//
#include <hip/hip_runtime.h>
#include <hip/hip_bf16.h>

#define N_NODES 120000
#define F       64

typedef __attribute__((ext_vector_type(8))) short bf16x8;   // 4 VGPRs
typedef __attribute__((ext_vector_type(4))) float f32x4;    // MFMA C/D

static __device__ __forceinline__ unsigned short f2bf(float x) {
    return __hip_bfloat16_raw(__float2bfloat16(x)).x;   // RNE
}
static __device__ __forceinline__ float u2f(unsigned int x) {
    return __uint_as_float(x);
}

// Kernel 1 (fused prep + MFMA GEMM):
//   T16 = bf16(feat @ theta_w); B16 = bf16(T + feat @ phi_w + theta_b + phi_b)
// Weights staged in LDS per block (32 KB, coalesced); each wave builds its
// MFMA B-operand fragments from LDS — removes the separate prep dispatch.
__global__ __launch_bounds__(256) void edgeconv_mfma(
    const float* __restrict__ feat,
    const float* __restrict__ theta_w,
    const float* __restrict__ phi_w,
    const float* __restrict__ theta_b,
    const float* __restrict__ phi_b,
    unsigned short* __restrict__ T16,
    unsigned short* __restrict__ B16)
{
    __shared__ float wlds[2 * F * F];   // [0]=theta (4096 f32), [1]=phi

    const int tid  = threadIdx.x;
    const int lane = tid & 63;
    const int wv   = tid >> 6;
    const int tile = blockIdx.x * 4 + wv;
    const int r0   = tile * 16;

    // Stage both weight matrices: 8192 floats = 2048 float4, 256 threads.
    {
        float4* dst = (float4*)wlds;
        const float4* st = (const float4*)theta_w;
        const float4* sp = (const float4*)phi_w;
        #pragma unroll
        for (int i = 0; i < 4; ++i)
            dst[tid + 256 * i] = st[tid + 256 * i];
        #pragma unroll
        for (int i = 0; i < 4; ++i)
            dst[1024 + tid + 256 * i] = sp[tid + 256 * i];
    }
    __syncthreads();

    // Build MFMA B-fragments from LDS:
    // wt[c][kb] elem e = W[kb*32 + (lane>>4)*8 + e][c*16 + (lane&15)]
    const int hi8  = (lane >> 4) * 8;
    const int lo16 = lane & 15;
    bf16x8 wt[4][2], wp[4][2];
    #pragma unroll
    for (int c = 0; c < 4; ++c) {
        #pragma unroll
        for (int kb = 0; kb < 2; ++kb) {
            const int kbase = kb * 32 + hi8;
            const int col   = c * 16 + lo16;
            bf16x8 vt, vp;
            #pragma unroll
            for (int e = 0; e < 8; ++e) {
                vt[e] = (short)f2bf(wlds[(kbase + e) * F + col]);
                vp[e] = (short)f2bf(wlds[F * F + (kbase + e) * F + col]);
            }
            wt[c][kb] = vt;
            wp[c][kb] = vp;
        }
    }

    // A fragments: lane holds row (lane&15), k = (lane>>4)*8 + e (+32 for kb=1).
    const int arow = r0 + lo16;
    const float4* f0 = (const float4*)(feat + arow * F + hi8);
    const float4* f1 = (const float4*)(feat + arow * F + 32 + hi8);
    float4 a0 = f0[0], a1 = f0[1];
    float4 a2 = f1[0], a3 = f1[1];
    bf16x8 afr0, afr1;
    afr0[0]=(short)f2bf(a0.x); afr0[1]=(short)f2bf(a0.y); afr0[2]=(short)f2bf(a0.z); afr0[3]=(short)f2bf(a0.w);
    afr0[4]=(short)f2bf(a1.x); afr0[5]=(short)f2bf(a1.y); afr0[6]=(short)f2bf(a1.z); afr0[7]=(short)f2bf(a1.w);
    afr1[0]=(short)f2bf(a2.x); afr1[1]=(short)f2bf(a2.y); afr1[2]=(short)f2bf(a2.z); afr1[3]=(short)f2bf(a2.w);
    afr1[4]=(short)f2bf(a3.x); afr1[5]=(short)f2bf(a3.y); afr1[6]=(short)f2bf(a3.z); afr1[7]=(short)f2bf(a3.w);

    f32x4 accT[4], accP[4];
    #pragma unroll
    for (int c = 0; c < 4; ++c) { accT[c] = (f32x4)(0.f); accP[c] = (f32x4)(0.f); }

    #pragma unroll
    for (int c = 0; c < 4; ++c) {
        accT[c] = __builtin_amdgcn_mfma_f32_16x16x32_bf16(afr0, wt[c][0], accT[c], 0, 0, 0);
        accT[c] = __builtin_amdgcn_mfma_f32_16x16x32_bf16(afr1, wt[c][1], accT[c], 0, 0, 0);
        accP[c] = __builtin_amdgcn_mfma_f32_16x16x32_bf16(afr0, wp[c][0], accP[c], 0, 0, 0);
        accP[c] = __builtin_amdgcn_mfma_f32_16x16x32_bf16(afr1, wp[c][1], accP[c], 0, 0, 0);
    }

    // Epilogue: D layout col = lane&15, row = (lane>>4)*4 + reg.
    const int rowbase = (lane >> 4) * 4;
    #pragma unroll
    for (int c = 0; c < 4; ++c) {
        const int col  = c * 16 + lo16;
        const float bo = theta_b[col] + phi_b[col];
        #pragma unroll
        for (int rg = 0; rg < 4; ++rg) {
            const int r = r0 + rowbase + rg;
            const float t = accT[c][rg];
            T16[r * F + col] = f2bf(t);
            B16[r * F + col] = f2bf(t + accP[c][rg] + bo);
        }
    }
}

// Kernel 2: out[v][o] = B[v][o] - min_k T[nbr[v][k]][o]
// 8 nodes/wave, 8 lanes/node, uint4 gathers (8 random 128B rows / instruction).
__global__ __launch_bounds__(256) void edgeconv_minmax(
    const int* __restrict__ nbr,              // [N,16] int32
    const unsigned short* __restrict__ T16,   // [N,64] bf16
    const unsigned short* __restrict__ B16,   // [N,64] bf16
    float* __restrict__ out)                  // [N,64] f32
{
    const int tid  = threadIdx.x;
    const int lane = tid & 63;
    const int wv   = tid >> 6;
    const int sub  = lane >> 3;      // node within wave, 0..7
    const int j    = lane & 7;       // lane covers cols 8j..8j+7 (16B)
    const int v    = blockIdx.x * 32 + wv * 8 + sub;

    // 16 neighbor indices (8 lanes/node same addr -> broadcast)
    const int4* nb4 = (const int4*)(nbr + v * 16);
    int4 i0 = nb4[0], i1 = nb4[1], i2 = nb4[2], i3 = nb4[3];
    int idx[16] = { i0.x, i0.y, i0.z, i0.w,
                    i1.x, i1.y, i1.z, i1.w,
                    i2.x, i2.y, i2.z, i2.w,
                    i3.x, i3.y, i3.z, i3.w };

    const char* tb = (const char*)T16 + (j << 4);

    // 16 independent 16B gathers per lane (issued before consumption).
    uint4 u[16];
    #pragma unroll
    for (int k = 0; k < 16; ++k)
        u[k] = *(const uint4*)(tb + (((unsigned int)idx[k]) << 7));

    // 8 running mins: even cols via <<16, odd cols via raw-as-f32
    // (raw dword's high half IS a valid f32; low-mantissa garbage <= 2^-8 rel).
    float mn[8];
    mn[0] = u2f(u[0].x << 16); mn[1] = u2f(u[0].x);
    mn[2] = u2f(u[0].y << 16); mn[3] = u2f(u[0].y);
    mn[4] = u2f(u[0].z << 16); mn[5] = u2f(u[0].z);
    mn[6] = u2f(u[0].w << 16); mn[7] = u2f(u[0].w);
    #pragma unroll
    for (int k = 1; k < 16; ++k) {
        mn[0] = fminf(mn[0], u2f(u[k].x << 16)); mn[1] = fminf(mn[1], u2f(u[k].x));
        mn[2] = fminf(mn[2], u2f(u[k].y << 16)); mn[3] = fminf(mn[3], u2f(u[k].y));
        mn[4] = fminf(mn[4], u2f(u[k].z << 16)); mn[5] = fminf(mn[5], u2f(u[k].z));
        mn[6] = fminf(mn[6], u2f(u[k].w << 16)); mn[7] = fminf(mn[7], u2f(u[k].w));
    }

    const uint4 bu = *(const uint4*)((const char*)B16 + (((unsigned int)v) << 7) + (j << 4));
    float4 r0, r1;
    r0.x = u2f(bu.x << 16)         - mn[0];
    r0.y = u2f(bu.x & 0xffff0000u) - mn[1];
    r0.z = u2f(bu.y << 16)         - mn[2];
    r0.w = u2f(bu.y & 0xffff0000u) - mn[3];
    r1.x = u2f(bu.z << 16)         - mn[4];
    r1.y = u2f(bu.z & 0xffff0000u) - mn[5];
    r1.z = u2f(bu.w << 16)         - mn[6];
    r1.w = u2f(bu.w & 0xffff0000u) - mn[7];

    float* op = out + v * F + j * 8;
    *(float4*)op       = r0;
    *(float4*)(op + 4) = r1;
}

extern "C" void kernel_launch(void* const* d_in, const int* in_sizes, int n_in,
                              void* d_out, int out_size, void* d_ws, size_t ws_size,
                              hipStream_t stream) {
    const float* feat    = (const float*)d_in[0];
    const int*   nbr     = (const int*)  d_in[1];
    const float* theta_w = (const float*)d_in[2];
    const float* theta_b = (const float*)d_in[3];
    const float* phi_w   = (const float*)d_in[4];
    const float* phi_b   = (const float*)d_in[5];
    float* out = (float*)d_out;

    unsigned short* T16 = (unsigned short*)d_ws;                   // 15.36 MB
    unsigned short* B16 = (unsigned short*)((char*)d_ws + 15360000);

    edgeconv_mfma<<<N_NODES / 64, 256, 0, stream>>>(feat, theta_w, phi_w,
                                                    theta_b, phi_b, T16, B16);
    edgeconv_minmax<<<N_NODES / 32, 256, 0, stream>>>(nbr, T16, B16, out);
}

// Round 11
// 53.599 us; speedup vs baseline: 1.7372x; 1.0347x over previous
//
#include <hip/hip_runtime.h>
#include <hip/hip_bf16.h>

#define N_NODES 120000
#define F       64
#define NTILES  (N_NODES / 16)   // 7500 16-row tiles -> 1875 tile-groups of 4
#define GRID1   235              // persistent blocks for kernel 1

typedef __attribute__((ext_vector_type(8))) short bf16x8;   // 4 VGPRs
typedef __attribute__((ext_vector_type(4))) float f32x4;    // MFMA C/D

static __device__ __forceinline__ unsigned short f2bf(float x) {
    return __hip_bfloat16_raw(__float2bfloat16(x)).x;   // RNE
}
static __device__ __forceinline__ float u2f(unsigned int x) {
    return __uint_as_float(x);
}

// Kernel 1 (persistent MFMA GEMM, fused weight prep):
//   T16 = bf16(feat @ theta_w); B16 = bf16(T + feat @ phi_w + theta_b + phi_b)
// Fragment build is COOPERATIVE (256 threads fill the 16 KB wfrag layout in LDS,
// 16B vector writes), then each lane reads its 16 fragments once (ds_read_b128)
// and keeps them in registers across a grid-stride loop over row tiles.
__global__ __launch_bounds__(256) void edgeconv_mfma(
    const float* __restrict__ feat,
    const float* __restrict__ theta_w,
    const float* __restrict__ phi_w,
    const float* __restrict__ theta_b,
    const float* __restrict__ phi_b,
    unsigned short* __restrict__ T16,
    unsigned short* __restrict__ B16)
{
    __shared__ unsigned short wfrag[16 * 64 * 8];   // [slot][lane][8] bf16 = 16 KB

    const int tid  = threadIdx.x;
    const int lane = tid & 63;
    const int wv   = tid >> 6;
    const int lo16 = lane & 15;
    const int hi8  = (lane >> 4) * 8;

    // Cooperative build: 1024 fragment entries, 4 per thread.
    // slot = (mat*4 + c)*2 + kb ; entry elem e = W[kb*32+(l>>4)*8+e][c*16+(l&15)]
    #pragma unroll
    for (int i = 0; i < 4; ++i) {
        const int eidx = tid + 256 * i;
        const int sl   = eidx >> 6, ln = eidx & 63;
        const int mat  = sl >> 3, c = (sl >> 1) & 3, kb = sl & 1;
        const float* W = mat ? phi_w : theta_w;
        const int k0   = kb * 32 + ((ln >> 4) * 8);
        const int col  = c * 16 + (ln & 15);
        bf16x8 v;
        #pragma unroll
        for (int e = 0; e < 8; ++e)
            v[e] = (short)f2bf(W[(k0 + e) * F + col]);
        ((bf16x8*)wfrag)[eidx] = v;
    }
    __syncthreads();

    // Each lane: 16 x ds_read_b128, fragments live in VGPRs for all tiles.
    bf16x8 wt[4][2], wp[4][2];
    #pragma unroll
    for (int c = 0; c < 4; ++c) {
        #pragma unroll
        for (int kb = 0; kb < 2; ++kb) {
            wt[c][kb] = ((bf16x8*)wfrag)[(((c << 1) | kb)) * 64 + lane];
            wp[c][kb] = ((bf16x8*)wfrag)[(8 + ((c << 1) | kb)) * 64 + lane];
        }
    }

    // Hoisted bias per column.
    float bo[4];
    #pragma unroll
    for (int c = 0; c < 4; ++c)
        bo[c] = theta_b[c * 16 + lo16] + phi_b[c * 16 + lo16];

    const int rowbase = (lane >> 4) * 4;

    for (int tile = blockIdx.x * 4 + wv; tile < NTILES; tile += GRID1 * 4) {
        const int r0   = tile * 16;
        const int arow = r0 + lo16;

        const float4* f0 = (const float4*)(feat + arow * F + hi8);
        const float4* f1 = (const float4*)(feat + arow * F + 32 + hi8);
        float4 a0 = f0[0], a1 = f0[1];
        float4 a2 = f1[0], a3 = f1[1];
        bf16x8 afr0, afr1;
        afr0[0]=(short)f2bf(a0.x); afr0[1]=(short)f2bf(a0.y); afr0[2]=(short)f2bf(a0.z); afr0[3]=(short)f2bf(a0.w);
        afr0[4]=(short)f2bf(a1.x); afr0[5]=(short)f2bf(a1.y); afr0[6]=(short)f2bf(a1.z); afr0[7]=(short)f2bf(a1.w);
        afr1[0]=(short)f2bf(a2.x); afr1[1]=(short)f2bf(a2.y); afr1[2]=(short)f2bf(a2.z); afr1[3]=(short)f2bf(a2.w);
        afr1[4]=(short)f2bf(a3.x); afr1[5]=(short)f2bf(a3.y); afr1[6]=(short)f2bf(a3.z); afr1[7]=(short)f2bf(a3.w);

        f32x4 accT[4], accP[4];
        #pragma unroll
        for (int c = 0; c < 4; ++c) { accT[c] = (f32x4)(0.f); accP[c] = (f32x4)(0.f); }

        #pragma unroll
        for (int c = 0; c < 4; ++c) {
            accT[c] = __builtin_amdgcn_mfma_f32_16x16x32_bf16(afr0, wt[c][0], accT[c], 0, 0, 0);
            accT[c] = __builtin_amdgcn_mfma_f32_16x16x32_bf16(afr1, wt[c][1], accT[c], 0, 0, 0);
            accP[c] = __builtin_amdgcn_mfma_f32_16x16x32_bf16(afr0, wp[c][0], accP[c], 0, 0, 0);
            accP[c] = __builtin_amdgcn_mfma_f32_16x16x32_bf16(afr1, wp[c][1], accP[c], 0, 0, 0);
        }

        // Epilogue: D layout col = lane&15, row = (lane>>4)*4 + reg.
        #pragma unroll
        for (int c = 0; c < 4; ++c) {
            const int col = c * 16 + lo16;
            #pragma unroll
            for (int rg = 0; rg < 4; ++rg) {
                const int r = r0 + rowbase + rg;
                const float t = accT[c][rg];
                T16[r * F + col] = f2bf(t);
                B16[r * F + col] = f2bf(t + accP[c][rg] + bo[c]);
            }
        }
    }
}

// Kernel 2: out[v][o] = B[v][o] - min_k T[nbr[v][k]][o]
// 8 nodes/wave, 8 lanes/node, uint4 gathers (8 random 128B rows / instruction).
__global__ __launch_bounds__(256) void edgeconv_minmax(
    const int* __restrict__ nbr,              // [N,16] int32
    const unsigned short* __restrict__ T16,   // [N,64] bf16
    const unsigned short* __restrict__ B16,   // [N,64] bf16
    float* __restrict__ out)                  // [N,64] f32
{
    const int tid  = threadIdx.x;
    const int lane = tid & 63;
    const int wv   = tid >> 6;
    const int sub  = lane >> 3;      // node within wave, 0..7
    const int j    = lane & 7;       // lane covers cols 8j..8j+7 (16B)
    const int v    = blockIdx.x * 32 + wv * 8 + sub;

    // 16 neighbor indices (8 lanes/node same addr -> broadcast)
    const int4* nb4 = (const int4*)(nbr + v * 16);
    int4 i0 = nb4[0], i1 = nb4[1], i2 = nb4[2], i3 = nb4[3];
    int idx[16] = { i0.x, i0.y, i0.z, i0.w,
                    i1.x, i1.y, i1.z, i1.w,
                    i2.x, i2.y, i2.z, i2.w,
                    i3.x, i3.y, i3.z, i3.w };

    const char* tb = (const char*)T16 + (j << 4);

    // 16 independent 16B gathers per lane (issued before consumption).
    uint4 u[16];
    #pragma unroll
    for (int k = 0; k < 16; ++k)
        u[k] = *(const uint4*)(tb + (((unsigned int)idx[k]) << 7));

    // 8 running mins: even cols via <<16, odd cols via raw-as-f32
    // (raw dword's high half IS a valid f32; low-mantissa garbage <= 2^-8 rel).
    float mn[8];
    mn[0] = u2f(u[0].x << 16); mn[1] = u2f(u[0].x);
    mn[2] = u2f(u[0].y << 16); mn[3] = u2f(u[0].y);
    mn[4] = u2f(u[0].z << 16); mn[5] = u2f(u[0].z);
    mn[6] = u2f(u[0].w << 16); mn[7] = u2f(u[0].w);
    #pragma unroll
    for (int k = 1; k < 16; ++k) {
        mn[0] = fminf(mn[0], u2f(u[k].x << 16)); mn[1] = fminf(mn[1], u2f(u[k].x));
        mn[2] = fminf(mn[2], u2f(u[k].y << 16)); mn[3] = fminf(mn[3], u2f(u[k].y));
        mn[4] = fminf(mn[4], u2f(u[k].z << 16)); mn[5] = fminf(mn[5], u2f(u[k].z));
        mn[6] = fminf(mn[6], u2f(u[k].w << 16)); mn[7] = fminf(mn[7], u2f(u[k].w));
    }

    const uint4 bu = *(const uint4*)((const char*)B16 + (((unsigned int)v) << 7) + (j << 4));
    float4 r0, r1;
    r0.x = u2f(bu.x << 16)         - mn[0];
    r0.y = u2f(bu.x & 0xffff0000u) - mn[1];
    r0.z = u2f(bu.y << 16)         - mn[2];
    r0.w = u2f(bu.y & 0xffff0000u) - mn[3];
    r1.x = u2f(bu.z << 16)         - mn[4];
    r1.y = u2f(bu.z & 0xffff0000u) - mn[5];
    r1.z = u2f(bu.w << 16)         - mn[6];
    r1.w = u2f(bu.w & 0xffff0000u) - mn[7];

    float* op = out + v * F + j * 8;
    *(float4*)op       = r0;
    *(float4*)(op + 4) = r1;
}

extern "C" void kernel_launch(void* const* d_in, const int* in_sizes, int n_in,
                              void* d_out, int out_size, void* d_ws, size_t ws_size,
                              hipStream_t stream) {
    const float* feat    = (const float*)d_in[0];
    const int*   nbr     = (const int*)  d_in[1];
    const float* theta_w = (const float*)d_in[2];
    const float* theta_b = (const float*)d_in[3];
    const float* phi_w   = (const float*)d_in[4];
    const float* phi_b   = (const float*)d_in[5];
    float* out = (float*)d_out;

    unsigned short* T16 = (unsigned short*)d_ws;                   // 15.36 MB
    unsigned short* B16 = (unsigned short*)((char*)d_ws + 15360000);

    edgeconv_mfma<<<GRID1, 256, 0, stream>>>(feat, theta_w, phi_w,
                                             theta_b, phi_b, T16, B16);
    edgeconv_minmax<<<N_NODES / 32, 256, 0, stream>>>(nbr, T16, B16, out);
}